// Round 1
// baseline (548.182 us; speedup 1.0000x reference)
//
#include <hip/hip_runtime.h>

#define LTOT 110592   // 48*48*48
#define NT   1728     // LTOT/64
#define EPSV 1e-5f

__device__ __forceinline__ unsigned encf(float f) {
  unsigned u = __float_as_uint(f);
  return (u & 0x80000000u) ? ~u : (u | 0x80000000u);
}
__device__ __forceinline__ float decf(unsigned u) {
  return (u & 0x80000000u) ? __uint_as_float(u & 0x7FFFFFFFu)
                           : __uint_as_float(~u);
}

// ---------------- K1: Bm = WB@X + bB, V = WV@X + bV, fused rowmax(Bm) ---------
// grid (216, B, 2): z=0 -> Bm (+rowmax atomics), z=1 -> V. 8 tiles of 64 cols each.
__global__ __launch_bounds__(256, 2) void k1_proj(
    const float* __restrict__ x,
    const float* __restrict__ WB_, const float* __restrict__ bB_,
    const float* __restrict__ WV_, const float* __restrict__ bV_,
    float* __restrict__ bm, float* __restrict__ vv,
    unsigned* __restrict__ rowmax)
{
  __shared__ __align__(16) float Ws[128][68];  // W^T: [c][r], pad 68 for banks
  __shared__ __align__(16) float Xs[128][64];  // [c][col]
  const int tid  = threadIdx.x;
  const int b    = blockIdx.y;
  const int half = blockIdx.z;
  const float* __restrict__ Wp = half ? WV_ : WB_;
  const float* __restrict__ bp = half ? bV_ : bB_;
  float* __restrict__ outp     = half ? vv  : bm;

  // stage W^T once per block (64 rows x 128 c)
  for (int k = 0; k < 32; ++k) {
    int idx = tid + k * 256;            // 0..8191
    Ws[idx & 127][idx >> 7] = Wp[idx];  // coalesced global read
  }

  const int r0 = (tid >> 4) << 2;   // 0..60
  const int c0 = (tid & 15) << 2;   // 0..60
  const float bias[4] = { bp[r0], bp[r0+1], bp[r0+2], bp[r0+3] };
  float rmx[4] = { -1e30f, -1e30f, -1e30f, -1e30f };
  const int col = tid & 63, cbase = tid >> 6;

  for (int t = 0; t < 8; ++t) {
    const int l0 = (blockIdx.x * 8 + t) * 64;
    __syncthreads();
    const float* xp = x + (size_t)b * 128 * LTOT + l0 + col;
    #pragma unroll
    for (int kk = 0; kk < 32; ++kk)
      Xs[cbase + kk * 4][col] = xp[(size_t)(cbase + kk * 4) * LTOT];
    __syncthreads();

    float acc[4][4];
    #pragma unroll
    for (int i = 0; i < 4; ++i)
      #pragma unroll
      for (int j = 0; j < 4; ++j) acc[i][j] = 0.f;

    #pragma unroll 4
    for (int c = 0; c < 128; ++c) {
      const float4 w  = *(const float4*)&Ws[c][r0];
      const float4 xv = *(const float4*)&Xs[c][c0];
      const float wr[4] = { w.x, w.y, w.z, w.w };
      const float xr[4] = { xv.x, xv.y, xv.z, xv.w };
      #pragma unroll
      for (int i = 0; i < 4; ++i)
        #pragma unroll
        for (int j = 0; j < 4; ++j) acc[i][j] += wr[i] * xr[j];
    }
    #pragma unroll
    for (int i = 0; i < 4; ++i) {
      float v0 = acc[i][0] + bias[i], v1 = acc[i][1] + bias[i];
      float v2 = acc[i][2] + bias[i], v3 = acc[i][3] + bias[i];
      *(float4*)&outp[((size_t)b * 64 + r0 + i) * LTOT + l0 + c0] =
          make_float4(v0, v1, v2, v3);
      if (half == 0)
        rmx[i] = fmaxf(rmx[i], fmaxf(fmaxf(v0, v1), fmaxf(v2, v3)));
    }
  }
  if (half == 0) {
    #pragma unroll
    for (int i = 0; i < 4; ++i) {
      float m = rmx[i];
      #pragma unroll
      for (int off = 1; off < 16; off <<= 1) m = fmaxf(m, __shfl_xor(m, off));
      if ((tid & 15) == 0) atomicMax(&rowmax[b * 64 + r0 + i], encf(m));
    }
  }
}

// ---------------- K2: M[c,n] = sum_l X[c,l]*exp(Bm[n,l]-max_n); partial sumexp -
// grid (144, B), 12 tiles each. partials: mpart[b][blk][128][64], separt[b][blk][64]
__global__ __launch_bounds__(256, 3) void k2_m(
    const float* __restrict__ x, const float* __restrict__ bm,
    const unsigned* __restrict__ rowmax,
    float* __restrict__ mpart, float* __restrict__ separt)
{
  __shared__ __align__(16) float Xt[64][132];  // [col][c]
  __shared__ __align__(16) float Es[64][68];   // [col][n]
  const int tid = threadIdx.x, b = blockIdx.y, blk = blockIdx.x;
  const int col = tid & 63, nset = tid >> 6;
  float rmax[16];
  #pragma unroll
  for (int k = 0; k < 16; ++k) rmax[k] = decf(rowmax[b * 64 + nset * 16 + k]);

  const int c0 = (tid & 15) * 8;   // 0..120
  const int n0 = (tid >> 4) * 4;   // 0..60
  float acc[8][4];
  #pragma unroll
  for (int i = 0; i < 8; ++i)
    #pragma unroll
    for (int j = 0; j < 4; ++j) acc[i][j] = 0.f;
  float se[16];
  #pragma unroll
  for (int k = 0; k < 16; ++k) se[k] = 0.f;

  for (int t = 0; t < 12; ++t) {
    const int l0 = (blk * 12 + t) * 64;
    __syncthreads();
    const float* xp = x + (size_t)b * 128 * LTOT + l0 + col;
    #pragma unroll
    for (int kk = 0; kk < 32; ++kk) {
      int c = (tid >> 6) + kk * 4;
      Xt[col][c] = xp[(size_t)c * LTOT];
    }
    const float* bmp = bm + (size_t)b * 64 * LTOT + l0 + col;
    #pragma unroll
    for (int kk = 0; kk < 16; ++kk) {
      int n = nset * 16 + kk;
      float e = __expf(bmp[(size_t)n * LTOT] - rmax[kk]);
      Es[col][n] = e;
      se[kk] += e;
    }
    __syncthreads();
    #pragma unroll 2
    for (int cc = 0; cc < 64; ++cc) {
      const float4 xa = *(const float4*)&Xt[cc][c0];
      const float4 xb = *(const float4*)&Xt[cc][c0 + 4];
      const float4 ev = *(const float4*)&Es[cc][n0];
      const float xr[8] = { xa.x, xa.y, xa.z, xa.w, xb.x, xb.y, xb.z, xb.w };
      const float er[4] = { ev.x, ev.y, ev.z, ev.w };
      #pragma unroll
      for (int i = 0; i < 8; ++i)
        #pragma unroll
        for (int j = 0; j < 4; ++j) acc[i][j] += xr[i] * er[j];
    }
  }
  float* mp = mpart + ((size_t)(b * 144 + blk)) * 8192;
  #pragma unroll
  for (int i = 0; i < 8; ++i)
    *(float4*)&mp[(c0 + i) * 64 + n0] =
        make_float4(acc[i][0], acc[i][1], acc[i][2], acc[i][3]);
  // reduce sumexp across the 64 lanes (=64 cols) of each wave
  #pragma unroll
  for (int kk = 0; kk < 16; ++kk) {
    float s = se[kk];
    #pragma unroll
    for (int off = 1; off < 64; off <<= 1) s += __shfl_xor(s, off);
    if ((tid & 63) == 0)
      separt[((size_t)(b * 144 + blk)) * 64 + nset * 16 + kk] = s;
  }
}

// ---------------- K3a: reduce M partials & sumexp partials ---------------------
__global__ void k3a_reduce(const float* __restrict__ mpart,
                           const float* __restrict__ separt,
                           float* __restrict__ msum, float* __restrict__ sesum)
{
  const int b = blockIdx.y;
  if (blockIdx.x < 32) {
    int idx = blockIdx.x * 256 + threadIdx.x;  // 0..8191
    float s = 0.f;
    for (int k = 0; k < 144; ++k)
      s += mpart[((size_t)(b * 144 + k)) * 8192 + idx];
    msum[b * 8192 + idx] = s;
  } else if (threadIdx.x < 64) {
    float s = 0.f;
    for (int k = 0; k < 144; ++k)
      s += separt[((size_t)(b * 144 + k)) * 64 + threadIdx.x];
    sesum[b * 64 + threadIdx.x] = s;
  }
}

// ---------------- K3b: Gt[n,m] = (WA@M)[m,n]/sumexp[n] + bA[m] ----------------
__global__ void k3b_g(const float* __restrict__ WA_, const float* __restrict__ bA_,
                      const float* __restrict__ msum, const float* __restrict__ sesum,
                      float* __restrict__ gt)
{
  const int b = blockIdx.y;
  const int idx = blockIdx.x * 256 + threadIdx.x;  // 0..8191
  const int m = idx >> 6, n = idx & 63;
  float s = 0.f;
  #pragma unroll 4
  for (int c = 0; c < 128; ++c) s += WA_[m * 128 + c] * msum[b * 8192 + c * 64 + n];
  gt[(size_t)b * 8192 + n * 128 + m] = s / sesum[b * 64 + n] + bA_[m];
}

// ---------------- K4: attn_vec softmax + Z = G@attn_vec + partial stats -------
// grid (432, B), 4 tiles each. Z written to d_out.
__global__ __launch_bounds__(256, 2) void k4_z(
    const float* __restrict__ vbuf, const float* __restrict__ gt,
    float* __restrict__ zout, float* __restrict__ stats)
{
  __shared__ __align__(16) float Vs[64][64];    // [n][col]
  __shared__ __align__(16) float AVn[64][68];   // [n][col] = exp(v-max)
  __shared__ __align__(16) float Gs[64][132];   // [n][m]
  __shared__ __align__(16) float rs[64];        // 1/sum per col
  const int tid = threadIdx.x, b = blockIdx.y, blk = blockIdx.x;

  for (int k = 0; k < 32; ++k) {
    int idx = tid + k * 256;
    Gs[idx >> 7][idx & 127] = gt[(size_t)b * 8192 + idx];
  }
  const int m0 = (tid >> 4) * 8;   // 0..120
  const int c0 = (tid & 15) * 4;   // 0..60
  float sacc[8], ssacc[8];
  #pragma unroll
  for (int i = 0; i < 8; ++i) { sacc[i] = 0.f; ssacc[i] = 0.f; }

  for (int t = 0; t < 4; ++t) {
    const int l0 = (blk * 4 + t) * 64;
    __syncthreads();
    {
      int col = tid & 63, nb = tid >> 6;
      const float* vp = vbuf + (size_t)b * 64 * LTOT + l0 + col;
      #pragma unroll
      for (int kk = 0; kk < 16; ++kk)
        Vs[nb + kk * 4][col] = vp[(size_t)(nb + kk * 4) * LTOT];
    }
    __syncthreads();
    if (tid < 64) {
      float mx = -1e30f;
      #pragma unroll 8
      for (int n = 0; n < 64; ++n) mx = fmaxf(mx, Vs[n][tid]);
      float s = 0.f;
      #pragma unroll 8
      for (int n = 0; n < 64; ++n) {
        float e = __expf(Vs[n][tid] - mx);
        AVn[n][tid] = e;
        s += e;
      }
      rs[tid] = 1.0f / s;
    }
    __syncthreads();
    float acc[8][4];
    #pragma unroll
    for (int i = 0; i < 8; ++i)
      #pragma unroll
      for (int j = 0; j < 4; ++j) acc[i][j] = 0.f;
    #pragma unroll 2
    for (int n = 0; n < 64; ++n) {
      const float4 g1 = *(const float4*)&Gs[n][m0];
      const float4 g2 = *(const float4*)&Gs[n][m0 + 4];
      const float4 av = *(const float4*)&AVn[n][c0];
      const float gr[8] = { g1.x, g1.y, g1.z, g1.w, g2.x, g2.y, g2.z, g2.w };
      const float ar[4] = { av.x, av.y, av.z, av.w };
      #pragma unroll
      for (int i = 0; i < 8; ++i)
        #pragma unroll
        for (int j = 0; j < 4; ++j) acc[i][j] += gr[i] * ar[j];
    }
    const float rv[4] = { rs[c0], rs[c0 + 1], rs[c0 + 2], rs[c0 + 3] };
    #pragma unroll
    for (int i = 0; i < 8; ++i) {
      float z0 = acc[i][0] * rv[0], z1 = acc[i][1] * rv[1];
      float z2 = acc[i][2] * rv[2], z3 = acc[i][3] * rv[3];
      *(float4*)&zout[((size_t)(b * 128 + m0 + i)) * LTOT + l0 + c0] =
          make_float4(z0, z1, z2, z3);
      sacc[i] += z0 + z1 + z2 + z3;
      ssacc[i] += z0 * z0 + z1 * z1 + z2 * z2 + z3 * z3;
    }
  }
  #pragma unroll
  for (int i = 0; i < 8; ++i) {
    float s = sacc[i], ss = ssacc[i];
    #pragma unroll
    for (int off = 1; off < 16; off <<= 1) {
      s += __shfl_xor(s, off);
      ss += __shfl_xor(ss, off);
    }
    if ((tid & 15) == 0) {
      float* sp = stats + ((size_t)((b * 432 + blk) * 128 + m0 + i)) * 2;
      sp[0] = s;
      sp[1] = ss;
    }
  }
}

// ---------------- K5: reduce stats -> mean, rsqrt(var+eps) --------------------
__global__ void k5_stats(const float* __restrict__ stats, float* __restrict__ mr)
{
  const int tid = threadIdx.x;  // 256 = 2 batches * 128 rows
  const int b = tid >> 7, m = tid & 127;
  float s = 0.f, ss = 0.f;
  for (int k = 0; k < 432; ++k) {
    const float* p = stats + ((size_t)((b * 432 + k) * 128 + m)) * 2;
    s += p[0];
    ss += p[1];
  }
  const float mean = s / (float)LTOT;
  float var = ss / (float)LTOT - mean * mean;
  var = fmaxf(var, 0.f);
  mr[(b * 128 + m) * 2 + 0] = mean;
  mr[(b * 128 + m) * 2 + 1] = rsqrtf(var + EPSV);
}

// ---------------- K6: in-place instance-norm of d_out -------------------------
__global__ void k6_norm(const float* __restrict__ mr, float* __restrict__ out)
{
  const size_t tot4 = (size_t)2 * 128 * LTOT / 4;
  for (size_t i4 = (size_t)blockIdx.x * 256 + threadIdx.x; i4 < tot4;
       i4 += (size_t)gridDim.x * 256) {
    const size_t base = i4 * 4;
    const int row = (int)(base / LTOT);  // b*128+m
    const float mean = mr[row * 2 + 0];
    const float rsig = mr[row * 2 + 1];
    float4 z = *(float4*)&out[base];
    z.x = (z.x - mean) * rsig;
    z.y = (z.y - mean) * rsig;
    z.z = (z.z - mean) * rsig;
    z.w = (z.w - mean) * rsig;
    *(float4*)&out[base] = z;
  }
}

extern "C" void kernel_launch(void* const* d_in, const int* in_sizes, int n_in,
                              void* d_out, int out_size, void* d_ws, size_t ws_size,
                              hipStream_t stream)
{
  const float* x  = (const float*)d_in[0];
  const float* WA = (const float*)d_in[1];
  const float* bA = (const float*)d_in[2];
  const float* WB = (const float*)d_in[3];
  const float* bB = (const float*)d_in[4];
  const float* WV = (const float*)d_in[5];
  const float* bV = (const float*)d_in[6];
  float* out = (float*)d_out;

  float* w = (float*)d_ws;
  const size_t nBmV = (size_t)2 * 64 * LTOT;  // 14,155,776 floats
  float*    bmv    = w;
  float*    vv     = bmv + nBmV;
  unsigned* rowmax = (unsigned*)(vv + nBmV);
  float*    separt = (float*)(rowmax + 256);
  float*    sesum  = separt + (size_t)2 * 144 * 64;
  float*    mpart  = sesum + 256;
  float*    msum   = mpart + (size_t)2 * 144 * 8192;
  float*    gt     = msum + (size_t)2 * 8192;
  float*    stats  = gt + (size_t)2 * 8192;
  float*    mr     = stats + (size_t)2 * 432 * 128 * 2;

  hipMemsetAsync(rowmax, 0, 128 * sizeof(unsigned), stream);
  k1_proj<<<dim3(216, 2, 2), 256, 0, stream>>>(x, WB, bB, WV, bV, bmv, vv, rowmax);
  k2_m<<<dim3(144, 2), 256, 0, stream>>>(x, bmv, rowmax, mpart, separt);
  k3a_reduce<<<dim3(33, 2), 256, 0, stream>>>(mpart, separt, msum, sesum);
  k3b_g<<<dim3(32, 2), 256, 0, stream>>>(WA, bA, msum, sesum, gt);
  k4_z<<<dim3(432, 2), 256, 0, stream>>>(vv, gt, out, stats);
  k5_stats<<<1, 256, 0, stream>>>(stats, mr);
  k6_norm<<<dim3(2048), 256, 0, stream>>>(mr, out);
}

// Round 2
// 528.081 us; speedup vs baseline: 1.0381x; 1.0381x over previous
//
#include <hip/hip_runtime.h>
#include <hip/hip_bf16.h>

#define LTOT 110592   // 48*48*48
#define EPSV 1e-5f

__device__ __forceinline__ unsigned encf(float f) {
  unsigned u = __float_as_uint(f);
  return (u & 0x80000000u) ? ~u : (u | 0x80000000u);
}
__device__ __forceinline__ float decf(unsigned u) {
  return (u & 0x80000000u) ? __uint_as_float(u & 0x7FFFFFFFu)
                           : __uint_as_float(~u);
}
__device__ __forceinline__ unsigned short f2bf(float f) {
  __hip_bfloat16 h = __float2bfloat16(f);
  return *(unsigned short*)&h;
}
__device__ __forceinline__ void gl_lds4(const float* g, float* l) {
  __builtin_amdgcn_global_load_lds(
      (const __attribute__((address_space(1))) void*)g,
      (__attribute__((address_space(3))) void*)l, 4, 0, 0);
}

// ---------------- K1: Bm = WB@X + bB, V = WV@X + bV (fused, bf16 out) --------
// grid (864, B): each block does 2 tiles of 64 cols. 1 block/CU (128KB LDS).
__global__ __launch_bounds__(256, 1) void k1_proj(
    const float* __restrict__ x,
    const float* __restrict__ WB_, const float* __restrict__ bB_,
    const float* __restrict__ WV_, const float* __restrict__ bV_,
    unsigned short* __restrict__ bm16, unsigned short* __restrict__ vv16,
    unsigned* __restrict__ rowmax)
{
  __shared__ __align__(16) float Ws[2][128][64];  // [half][c][r], pitch 64: 2-way banks (free)
  __shared__ __align__(16) float Xs[2][128][64];  // [buf][c][l], linear for global_load_lds
  const int tid = threadIdx.x;
  const int b = blockIdx.y;
  const int lane = tid & 63;
  const int crow = tid >> 6;   // wave id 0..3

  // ---- stage W^T (both halves): gather rows, conflict-free LDS writes ----
  {
    const int r = tid & 63, q = tid >> 6;
    const int c0w = q * 32;
    #pragma unroll
    for (int h = 0; h < 2; ++h) {
      const float* Wg = h ? WV_ : WB_;
      #pragma unroll
      for (int j = 0; j < 8; ++j) {
        const float4 wv = *(const float4*)&Wg[r * 128 + c0w + j * 4];
        Ws[h][c0w + j * 4 + 0][r] = wv.x;
        Ws[h][c0w + j * 4 + 1][r] = wv.y;
        Ws[h][c0w + j * 4 + 2][r] = wv.z;
        Ws[h][c0w + j * 4 + 3][r] = wv.w;
      }
    }
  }
  const size_t xbase = (size_t)b * 128 * LTOT;
  const int l0base = blockIdx.x * 128;
  // prefetch tile 0
  {
    const float* xp = &x[xbase + l0base + lane];
    #pragma unroll
    for (int kk = 0; kk < 32; ++kk) {
      int c = crow + kk * 4;
      gl_lds4(xp + (size_t)c * LTOT, &Xs[0][c][lane]);
    }
  }
  const int r0 = (tid >> 4) << 2;   // 0..60
  const int l0q = (tid & 15) << 2;  // 0..60
  const float biasB[4] = { bB_[r0], bB_[r0+1], bB_[r0+2], bB_[r0+3] };
  const float biasV[4] = { bV_[r0], bV_[r0+1], bV_[r0+2], bV_[r0+3] };
  float rmx[4] = { -1e30f, -1e30f, -1e30f, -1e30f };
  __syncthreads();

  for (int t = 0; t < 2; ++t) {
    if (t == 0) {  // prefetch tile 1 (in flight during compute of tile 0)
      const float* xp = &x[xbase + l0base + 64 + lane];
      #pragma unroll
      for (int kk = 0; kk < 32; ++kk) {
        int c = crow + kk * 4;
        gl_lds4(xp + (size_t)c * LTOT, &Xs[1][c][lane]);
      }
    }
    float acc[2][4][4];
    #pragma unroll
    for (int h = 0; h < 2; ++h)
      #pragma unroll
      for (int i = 0; i < 4; ++i)
        #pragma unroll
        for (int j = 0; j < 4; ++j) acc[h][i][j] = 0.f;

    #pragma unroll 8
    for (int cc = 0; cc < 128; ++cc) {
      const float4 wb = *(const float4*)&Ws[0][cc][r0];
      const float4 wv = *(const float4*)&Ws[1][cc][r0];
      const float4 xv = *(const float4*)&Xs[t][cc][l0q];
      const float wbr[4] = { wb.x, wb.y, wb.z, wb.w };
      const float wvr[4] = { wv.x, wv.y, wv.z, wv.w };
      const float xr[4]  = { xv.x, xv.y, xv.z, xv.w };
      #pragma unroll
      for (int i = 0; i < 4; ++i)
        #pragma unroll
        for (int j = 0; j < 4; ++j) {
          acc[0][i][j] += wbr[i] * xr[j];
          acc[1][i][j] += wvr[i] * xr[j];
        }
    }
    const int l0 = l0base + t * 64;
    #pragma unroll
    for (int i = 0; i < 4; ++i) {
      float v0 = acc[0][i][0] + biasB[i], v1 = acc[0][i][1] + biasB[i];
      float v2 = acc[0][i][2] + biasB[i], v3 = acc[0][i][3] + biasB[i];
      ushort4 pk;
      pk.x = f2bf(v0); pk.y = f2bf(v1); pk.z = f2bf(v2); pk.w = f2bf(v3);
      *(ushort4*)&bm16[((size_t)b * 64 + r0 + i) * LTOT + l0 + l0q] = pk;
      rmx[i] = fmaxf(rmx[i], fmaxf(fmaxf(v0, v1), fmaxf(v2, v3)));
      float u0 = acc[1][i][0] + biasV[i], u1 = acc[1][i][1] + biasV[i];
      float u2 = acc[1][i][2] + biasV[i], u3 = acc[1][i][3] + biasV[i];
      ushort4 pv;
      pv.x = f2bf(u0); pv.y = f2bf(u1); pv.z = f2bf(u2); pv.w = f2bf(u3);
      *(ushort4*)&vv16[((size_t)b * 64 + r0 + i) * LTOT + l0 + l0q] = pv;
    }
    if (t == 0) __syncthreads();
  }
  #pragma unroll
  for (int i = 0; i < 4; ++i) {
    float m = rmx[i];
    #pragma unroll
    for (int off = 1; off < 16; off <<= 1) m = fmaxf(m, __shfl_xor(m, off));
    if ((tid & 15) == 0) atomicMax(&rowmax[b * 64 + r0 + i], encf(m));
  }
}

// ---------------- K2: M[c,n] = sum_l X[c,l]*exp(Bm[n,l]-max_n); partial sumexp -
// grid (432, B), 4 tiles each -> 3 blocks/CU resident.
__global__ __launch_bounds__(256, 3) void k2_m(
    const float* __restrict__ x, const __hip_bfloat16* __restrict__ bm,
    const unsigned* __restrict__ rowmax,
    float* __restrict__ mpart, float* __restrict__ separt)
{
  __shared__ __align__(16) float Xt[64][132];  // [l][c], pitch 132 (16B-aligned rows)
  __shared__ __align__(16) float Es[64][68];   // [l][n]
  const int tid = threadIdx.x, b = blockIdx.y, blk = blockIdx.x;
  const int col = tid & 63, nset = tid >> 6;
  float rmax[16];
  #pragma unroll
  for (int k = 0; k < 16; ++k) rmax[k] = decf(rowmax[b * 64 + nset * 16 + k]);

  const int cA = (tid & 15) * 4;    // 0..60   (16B-stride reads -> 2-way, free)
  const int cB = cA + 64;           // 64..124
  const int n0 = (tid >> 4) * 4;    // 0..60
  float acc[8][4];
  #pragma unroll
  for (int i = 0; i < 8; ++i)
    #pragma unroll
    for (int j = 0; j < 4; ++j) acc[i][j] = 0.f;
  float se[16];
  #pragma unroll
  for (int k = 0; k < 16; ++k) se[k] = 0.f;

  for (int t = 0; t < 4; ++t) {
    const int l0 = (blk * 4 + t) * 64;
    __syncthreads();
    const float* xp = x + (size_t)b * 128 * LTOT + l0 + col;
    #pragma unroll
    for (int kk = 0; kk < 32; ++kk) {
      int c = (tid >> 6) + kk * 4;
      Xt[col][c] = xp[(size_t)c * LTOT];
    }
    const __hip_bfloat16* bmp = bm + (size_t)b * 64 * LTOT + l0 + col;
    #pragma unroll
    for (int kk = 0; kk < 16; ++kk) {
      int n = nset * 16 + kk;
      float e = __expf(__bfloat162float(bmp[(size_t)n * LTOT]) - rmax[kk]);
      Es[col][n] = e;
      se[kk] += e;
    }
    __syncthreads();
    #pragma unroll 2
    for (int cc = 0; cc < 64; ++cc) {
      const float4 xa = *(const float4*)&Xt[cc][cA];
      const float4 xb = *(const float4*)&Xt[cc][cB];
      const float4 ev = *(const float4*)&Es[cc][n0];
      const float xr[8] = { xa.x, xa.y, xa.z, xa.w, xb.x, xb.y, xb.z, xb.w };
      const float er[4] = { ev.x, ev.y, ev.z, ev.w };
      #pragma unroll
      for (int i = 0; i < 8; ++i)
        #pragma unroll
        for (int j = 0; j < 4; ++j) acc[i][j] += xr[i] * er[j];
    }
  }
  float* mp = mpart + ((size_t)(b * 432 + blk)) * 8192;
  #pragma unroll
  for (int i = 0; i < 4; ++i)
    *(float4*)&mp[(cA + i) * 64 + n0] =
        make_float4(acc[i][0], acc[i][1], acc[i][2], acc[i][3]);
  #pragma unroll
  for (int i = 0; i < 4; ++i)
    *(float4*)&mp[(cB + i) * 64 + n0] =
        make_float4(acc[4 + i][0], acc[4 + i][1], acc[4 + i][2], acc[4 + i][3]);
  #pragma unroll
  for (int kk = 0; kk < 16; ++kk) {
    float s = se[kk];
    #pragma unroll
    for (int off = 1; off < 64; off <<= 1) s += __shfl_xor(s, off);
    if ((tid & 63) == 0)
      separt[((size_t)(b * 432 + blk)) * 64 + nset * 16 + kk] = s;
  }
}

// ---------------- K3a: partial reduce (432 -> 8 segs) + sumexp full reduce ----
__global__ void k3a_reduce(const float* __restrict__ mpart,
                           const float* __restrict__ separt,
                           float* __restrict__ mpart2, float* __restrict__ sesum)
{
  const int b = blockIdx.y, bx = blockIdx.x, tid = threadIdx.x;
  if (bx < 256) {
    const int seg = bx >> 5, chunk = bx & 31;
    const int idx = chunk * 256 + tid;
    float s = 0.f;
    for (int j = 0; j < 54; ++j)
      s += mpart[((size_t)(b * 432 + seg * 54 + j)) * 8192 + idx];
    mpart2[((size_t)(b * 8 + seg)) * 8192 + idx] = s;
  } else {
    const int n = tid >> 2, q = tid & 3;
    float s = 0.f;
    for (int k = q; k < 432; k += 4)
      s += separt[((size_t)(b * 432 + k)) * 64 + n];
    s += __shfl_xor(s, 1);
    s += __shfl_xor(s, 2);
    if (q == 0) sesum[b * 64 + n] = s;
  }
}

// ---------------- K3a2: 8 segs -> msum -----------------------------------------
__global__ void k3a2_reduce(const float* __restrict__ mpart2, float* __restrict__ msum)
{
  const int b = blockIdx.y;
  const int idx = blockIdx.x * 256 + threadIdx.x;
  float s = 0.f;
  #pragma unroll
  for (int k = 0; k < 8; ++k) s += mpart2[((size_t)(b * 8 + k)) * 8192 + idx];
  msum[(size_t)b * 8192 + idx] = s;
}

// ---------------- K3b: Gt[n,m] = (WA@M)[m,n]/sumexp[n] + bA[m] ----------------
__global__ void k3b_g(const float* __restrict__ WA_, const float* __restrict__ bA_,
                      const float* __restrict__ msum, const float* __restrict__ sesum,
                      float* __restrict__ gt)
{
  const int b = blockIdx.y;
  const int idx = blockIdx.x * 256 + threadIdx.x;  // 0..8191
  const int m = idx >> 6, n = idx & 63;
  float s = 0.f;
  #pragma unroll 4
  for (int c = 0; c < 128; ++c) s += WA_[m * 128 + c] * msum[b * 8192 + c * 64 + n];
  gt[(size_t)b * 8192 + n * 128 + m] = s / sesum[b * 64 + n] + bA_[m];
}

// ---------------- K4: attn_vec softmax (parallel) + Z = G@attn_vec + stats ----
__global__ __launch_bounds__(256, 2) void k4_z(
    const __hip_bfloat16* __restrict__ vbuf, const float* __restrict__ gt,
    float* __restrict__ zout, float* __restrict__ stats)
{
  __shared__ __align__(16) float Vs[64][68];    // [n][col^swz]
  __shared__ __align__(16) float AVn[64][68];   // [n][col^swz]
  __shared__ __align__(16) float Gs[64][132];   // [n][m]
  __shared__ float rs[64];
  const int tid = threadIdx.x, b = blockIdx.y, blk = blockIdx.x;

  for (int k = 0; k < 32; ++k) {
    int idx = tid + k * 256;
    Gs[idx >> 7][idx & 127] = gt[(size_t)b * 8192 + idx];
  }
  const int m0 = (tid >> 4) * 8;   // 0..120
  const int c0 = (tid & 15) * 4;   // 0..60
  const int colS = tid >> 2, sub = tid & 3;
  float sacc[8], ssacc[8];
  #pragma unroll
  for (int i = 0; i < 8; ++i) { sacc[i] = 0.f; ssacc[i] = 0.f; }

  for (int t = 0; t < 4; ++t) {
    const int l0 = (blk * 4 + t) * 64;
    __syncthreads();
    {
      const int col = tid & 63, nb = tid >> 6;
      const __hip_bfloat16* vp = vbuf + (size_t)b * 64 * LTOT + l0 + col;
      #pragma unroll
      for (int kk = 0; kk < 16; ++kk) {
        int n = nb + kk * 4;
        Vs[n][col ^ (((n >> 4) & 1) << 4)] = __bfloat162float(vp[(size_t)n * LTOT]);
      }
    }
    __syncthreads();
    {  // all-thread softmax over n: 4 threads per col
      const int cs = colS ^ ((sub & 1) << 4);
      float mx = -1e30f;
      #pragma unroll
      for (int k = 0; k < 16; ++k) mx = fmaxf(mx, Vs[sub * 16 + k][cs]);
      mx = fmaxf(mx, __shfl_xor(mx, 1));
      mx = fmaxf(mx, __shfl_xor(mx, 2));
      float s = 0.f;
      #pragma unroll
      for (int k = 0; k < 16; ++k) {
        float e = __expf(Vs[sub * 16 + k][cs] - mx);
        AVn[sub * 16 + k][cs] = e;
        s += e;
      }
      s += __shfl_xor(s, 1);
      s += __shfl_xor(s, 2);
      if (sub == 0) rs[colS] = 1.0f / s;
    }
    __syncthreads();
    float acc[8][4];
    #pragma unroll
    for (int i = 0; i < 8; ++i)
      #pragma unroll
      for (int j = 0; j < 4; ++j) acc[i][j] = 0.f;
    #pragma unroll 2
    for (int n = 0; n < 64; ++n) {
      const float4 g1 = *(const float4*)&Gs[n][m0];
      const float4 g2 = *(const float4*)&Gs[n][m0 + 4];
      const float4 av = *(const float4*)&AVn[n][c0 ^ (((n >> 4) & 1) << 4)];
      const float gr[8] = { g1.x, g1.y, g1.z, g1.w, g2.x, g2.y, g2.z, g2.w };
      const float ar[4] = { av.x, av.y, av.z, av.w };
      #pragma unroll
      for (int i = 0; i < 8; ++i)
        #pragma unroll
        for (int j = 0; j < 4; ++j) acc[i][j] += gr[i] * ar[j];
    }
    const float rv[4] = { rs[c0], rs[c0 + 1], rs[c0 + 2], rs[c0 + 3] };
    #pragma unroll
    for (int i = 0; i < 8; ++i) {
      float z0 = acc[i][0] * rv[0], z1 = acc[i][1] * rv[1];
      float z2 = acc[i][2] * rv[2], z3 = acc[i][3] * rv[3];
      *(float4*)&zout[((size_t)(b * 128 + m0 + i)) * LTOT + l0 + c0] =
          make_float4(z0, z1, z2, z3);
      sacc[i] += z0 + z1 + z2 + z3;
      ssacc[i] += z0 * z0 + z1 * z1 + z2 * z2 + z3 * z3;
    }
  }
  #pragma unroll
  for (int i = 0; i < 8; ++i) {
    float s = sacc[i], ss = ssacc[i];
    #pragma unroll
    for (int off = 1; off < 16; off <<= 1) {
      s += __shfl_xor(s, off);
      ss += __shfl_xor(ss, off);
    }
    if ((tid & 15) == 0) {
      float* sp = stats + ((size_t)(b * 128 + m0 + i) * 432 + blk) * 2;
      sp[0] = s;
      sp[1] = ss;
    }
  }
}

// ---------------- K5: reduce stats -> mean, rsqrt(var+eps) --------------------
// grid: 256 blocks (one per b*128+m), 64 threads, coalesced row reads.
__global__ void k5_stats(const float* __restrict__ stats, float* __restrict__ mr)
{
  const int row = blockIdx.x;
  const int tid = threadIdx.x;
  const float* p = stats + (size_t)row * 432 * 2;
  float s = 0.f, ss = 0.f;
  for (int k = tid; k < 432; k += 64) {
    s += p[k * 2];
    ss += p[k * 2 + 1];
  }
  #pragma unroll
  for (int off = 1; off < 64; off <<= 1) {
    s += __shfl_xor(s, off);
    ss += __shfl_xor(ss, off);
  }
  if (tid == 0) {
    const float mean = s / (float)LTOT;
    float var = fmaxf(ss / (float)LTOT - mean * mean, 0.f);
    mr[row * 2 + 0] = mean;
    mr[row * 2 + 1] = rsqrtf(var + EPSV);
  }
}

// ---------------- K6: in-place instance-norm of d_out -------------------------
__global__ void k6_norm(const float* __restrict__ mr, float* __restrict__ out)
{
  const size_t tot4 = (size_t)2 * 128 * LTOT / 4;
  for (size_t i4 = (size_t)blockIdx.x * 256 + threadIdx.x; i4 < tot4;
       i4 += (size_t)gridDim.x * 256) {
    const size_t base = i4 * 4;
    const int row = (int)(base / LTOT);  // b*128+m
    const float mean = mr[row * 2 + 0];
    const float rsig = mr[row * 2 + 1];
    float4 z = *(float4*)&out[base];
    z.x = (z.x - mean) * rsig;
    z.y = (z.y - mean) * rsig;
    z.z = (z.z - mean) * rsig;
    z.w = (z.w - mean) * rsig;
    *(float4*)&out[base] = z;
  }
}

extern "C" void kernel_launch(void* const* d_in, const int* in_sizes, int n_in,
                              void* d_out, int out_size, void* d_ws, size_t ws_size,
                              hipStream_t stream)
{
  const float* x  = (const float*)d_in[0];
  const float* WA = (const float*)d_in[1];
  const float* bA = (const float*)d_in[2];
  const float* WB = (const float*)d_in[3];
  const float* bB = (const float*)d_in[4];
  const float* WV = (const float*)d_in[5];
  const float* bV = (const float*)d_in[6];
  float* out = (float*)d_out;

  const size_t nBmV = (size_t)2 * 64 * LTOT;  // 14,155,776 elems
  unsigned short* bm16 = (unsigned short*)d_ws;
  unsigned short* vv16 = bm16 + nBmV;
  unsigned* rowmax = (unsigned*)(vv16 + nBmV);
  float* separt = (float*)(rowmax + 128);
  float* sesum  = separt + (size_t)2 * 432 * 64;
  float* mpart  = sesum + 128;
  float* mpart2 = mpart + (size_t)2 * 432 * 8192;
  float* msum   = mpart2 + (size_t)2 * 8 * 8192;
  float* gt     = msum + (size_t)2 * 8192;
  float* stats  = gt + (size_t)2 * 8192;
  float* mr     = stats + (size_t)2 * 128 * 432 * 2;

  hipMemsetAsync(rowmax, 0, 128 * sizeof(unsigned), stream);
  k1_proj<<<dim3(864, 2), 256, 0, stream>>>(x, WB, bB, WV, bV, bm16, vv16, rowmax);
  k2_m<<<dim3(432, 2), 256, 0, stream>>>(x, (const __hip_bfloat16*)bm16, rowmax, mpart, separt);
  k3a_reduce<<<dim3(257, 2), 256, 0, stream>>>(mpart, separt, mpart2, sesum);
  k3a2_reduce<<<dim3(32, 2), 256, 0, stream>>>(mpart2, msum);
  k3b_g<<<dim3(32, 2), 256, 0, stream>>>(WA, bA, msum, sesum, gt);
  k4_z<<<dim3(432, 2), 256, 0, stream>>>((const __hip_bfloat16*)vv16, gt, out, stats);
  k5_stats<<<256, 64, 0, stream>>>(stats, mr);
  k6_norm<<<dim3(2048), 256, 0, stream>>>(mr, out);
}

// Round 3
// 143.084 us; speedup vs baseline: 3.8312x; 3.6907x over previous
//
#include <hip/hip_runtime.h>

#define LTOT 110592   // 48*48*48
#define EPSV 1e-5f

typedef _Float16 f16;
typedef __attribute__((ext_vector_type(4))) _Float16 f16x4;
typedef __attribute__((ext_vector_type(8))) _Float16 f16x8;
typedef __attribute__((ext_vector_type(4))) float f32x4;

#define MFMA16(a, b, c) __builtin_amdgcn_mfma_f32_16x16x32_f16(a, b, c, 0, 0, 0)

__device__ __forceinline__ f16x8 ld_w8(const float* p) {
  const float4 a = *(const float4*)p;
  const float4 b = *(const float4*)(p + 4);
  f16x8 f;
  f[0] = (f16)a.x; f[1] = (f16)a.y; f[2] = (f16)a.z; f[3] = (f16)a.w;
  f[4] = (f16)b.x; f[5] = (f16)b.y; f[6] = (f16)b.z; f[7] = (f16)b.w;
  return f;
}

// ============ P1: Bm,V = W@X (MFMA f16); e=exp(Bm); M += X@e^T; V->ws ========
// grid (432, B), T=4 tiles of 64 cols. LDS 48KB -> 3 blocks/CU.
__global__ __launch_bounds__(256, 2) void p1_proj_m(
    const float* __restrict__ x,
    const float* __restrict__ WB_, const float* __restrict__ bB_,
    const float* __restrict__ WV_, const float* __restrict__ bV_,
    f16* __restrict__ vv, float* __restrict__ mpart, float* __restrict__ separt)
{
  __shared__ __align__(16) f16 XT[64 * 128];  // [l][c] swizzled (proj B-frags)
  __shared__ __align__(16) f16 XC[128 * 64];  // [c][l] swizzled (M A-frags)
  __shared__ __align__(16) f16 EL[64 * 64];   // e[n][l] swizzled (M B-frags)
  __shared__ __align__(16) f16 VL[64 * 64];   // v[n][l] swizzled (V store)
  const int tid = threadIdx.x, b = blockIdx.y, blk = blockIdx.x;
  const int ln = tid & 63, wid = tid >> 6;

  // W A-fragments in registers: this wave owns Bm rows [wid*16,+16) and V rows same
  f16x8 wbf[4], wvf[4];
  {
    const int row = wid * 16 + (ln & 15);
    const int cb = (ln >> 4) * 8;
    #pragma unroll
    for (int ks = 0; ks < 4; ++ks) {
      wbf[ks] = ld_w8(&WB_[row * 128 + ks * 32 + cb]);
      wvf[ks] = ld_w8(&WV_[row * 128 + ks * 32 + cb]);
    }
  }
  float biasB[4], biasV[4];
  #pragma unroll
  for (int r = 0; r < 4; ++r) {
    const int n = wid * 16 + (ln >> 4) * 4 + r;
    biasB[r] = bB_[n];
    biasV[r] = bV_[n];
  }

  f32x4 macc[2][4];
  #pragma unroll
  for (int i = 0; i < 2; ++i)
    #pragma unroll
    for (int j = 0; j < 4; ++j) macc[i][j] = (f32x4){0.f, 0.f, 0.f, 0.f};
  float se[4] = {0.f, 0.f, 0.f, 0.f};

  const int sc = tid >> 4;          // staging c base 0..15
  const int lq = (tid & 15) * 4;    // staging l quad
  const size_t xbase = (size_t)b * 128 * LTOT;

  for (int t = 0; t < 4; ++t) {
    const int l0 = (blk * 4 + t) * 64;
    __syncthreads();
    // ---- stage X tile: fp32 global -> f16 LDS in two layouts ----
    #pragma unroll
    for (int s = 0; s < 8; ++s) {
      const int c = sc + s * 16;
      const float4 v = *(const float4*)&x[xbase + (size_t)c * LTOT + l0 + lq];
      f16x4 qv;
      qv[0] = (f16)v.x; qv[1] = (f16)v.y; qv[2] = (f16)v.z; qv[3] = (f16)v.w;
      *(f16x4*)&XC[c * 64 + ((((lq >> 3) ^ (c & 7)) << 3) | (lq & 7))] = qv;
      XT[(lq + 0) * 128 + ((((c >> 3) ^ ((lq + 0) & 7)) << 3) | (c & 7))] = qv[0];
      XT[(lq + 1) * 128 + ((((c >> 3) ^ ((lq + 1) & 7)) << 3) | (c & 7))] = qv[1];
      XT[(lq + 2) * 128 + ((((c >> 3) ^ ((lq + 2) & 7)) << 3) | (c & 7))] = qv[2];
      XT[(lq + 3) * 128 + ((((c >> 3) ^ ((lq + 3) & 7)) << 3) | (c & 7))] = qv[3];
    }
    __syncthreads();
    // ---- projection: Bm,V 16x64 per wave (K=128) ----
    f32x4 accB[4], accV[4];
    #pragma unroll
    for (int ct = 0; ct < 4; ++ct) {
      accB[ct] = (f32x4){0.f, 0.f, 0.f, 0.f};
      accV[ct] = (f32x4){0.f, 0.f, 0.f, 0.f};
    }
    #pragma unroll
    for (int ks = 0; ks < 4; ++ks) {
      #pragma unroll
      for (int ct = 0; ct < 4; ++ct) {
        const int l = ct * 16 + (ln & 15);
        const int cblk = ks * 4 + (ln >> 4);
        const f16x8 bf = *(const f16x8*)&XT[l * 128 + ((cblk ^ (l & 7)) << 3)];
        accB[ct] = MFMA16(wbf[ks], bf, accB[ct]);
        accV[ct] = MFMA16(wvf[ks], bf, accV[ct]);
      }
    }
    // ---- e = exp(Bm+bias) -> EL; V+bias -> VL; sumexp partial ----
    #pragma unroll
    for (int ct = 0; ct < 4; ++ct) {
      const int l = ct * 16 + (ln & 15);
      #pragma unroll
      for (int r = 0; r < 4; ++r) {
        const int n = wid * 16 + (ln >> 4) * 4 + r;
        const int sidx = n * 64 + ((((l >> 3) ^ (n & 7)) << 3) | (l & 7));
        const float e = __expf(accB[ct][r] + biasB[r]);
        se[r] += e;
        EL[sidx] = (f16)e;
        VL[sidx] = (f16)(accV[ct][r] + biasV[r]);
      }
    }
    __syncthreads();
    // ---- V tile -> global (coalesced f16x8) ----
    {
      const int n = tid >> 2, lc = (tid & 3) * 16;
      const f16x8 v0 = *(const f16x8*)&VL[n * 64 + ((((lc >> 3) ^ (n & 7))) << 3)];
      const f16x8 v1 = *(const f16x8*)&VL[n * 64 + (((((lc >> 3) + 1) ^ (n & 7))) << 3)];
      f16* vp = vv + (size_t)(b * 64 + n) * LTOT + l0 + lc;
      *(f16x8*)&vp[0] = v0;
      *(f16x8*)&vp[8] = v1;
    }
    // ---- M[c,n] += X@e^T (K=64) ----
    #pragma unroll
    for (int ks = 0; ks < 2; ++ks) {
      const int lblk = ks * 4 + (ln >> 4);
      f16x8 af[2], bfm[4];
      #pragma unroll
      for (int crt = 0; crt < 2; ++crt) {
        const int c = (wid * 2 + crt) * 16 + (ln & 15);
        af[crt] = *(const f16x8*)&XC[c * 64 + ((lblk ^ (c & 7)) << 3)];
      }
      #pragma unroll
      for (int nct = 0; nct < 4; ++nct) {
        const int n = nct * 16 + (ln & 15);
        bfm[nct] = *(const f16x8*)&EL[n * 64 + ((lblk ^ (n & 7)) << 3)];
      }
      #pragma unroll
      for (int crt = 0; crt < 2; ++crt)
        #pragma unroll
        for (int nct = 0; nct < 4; ++nct)
          macc[crt][nct] = MFMA16(af[crt], bfm[nct], macc[crt][nct]);
    }
  }
  // ---- write M partial + sumexp partial ----
  float* mp = mpart + (size_t)(b * 432 + blk) * 8192;
  #pragma unroll
  for (int crt = 0; crt < 2; ++crt)
    #pragma unroll
    for (int nct = 0; nct < 4; ++nct)
      #pragma unroll
      for (int r = 0; r < 4; ++r) {
        const int c = (wid * 2 + crt) * 16 + (ln >> 4) * 4 + r;
        const int n = nct * 16 + (ln & 15);
        mp[c * 64 + n] = macc[crt][nct][r];
      }
  #pragma unroll
  for (int r = 0; r < 4; ++r) {
    float s = se[r];
    s += __shfl_xor(s, 1); s += __shfl_xor(s, 2);
    s += __shfl_xor(s, 4); s += __shfl_xor(s, 8);
    if ((ln & 15) == 0)
      separt[(size_t)(b * 432 + blk) * 64 + wid * 16 + (ln >> 4) * 4 + r] = s;
  }
}

// ============ P2a: M partials 432 -> 8 segs; sumexp 432 -> 1 =================
__global__ void p2a(const float* __restrict__ mpart, const float* __restrict__ separt,
                    float* __restrict__ mpart2, float* __restrict__ sesum)
{
  const int b = blockIdx.y, bx = blockIdx.x, tid = threadIdx.x;
  if (bx < 256) {
    const int seg = bx >> 5, chunk = bx & 31;
    const int idx = chunk * 256 + tid;
    float s = 0.f;
    for (int j = 0; j < 54; ++j)
      s += mpart[(size_t)(b * 432 + seg * 54 + j) * 8192 + idx];
    mpart2[(size_t)(b * 8 + seg) * 8192 + idx] = s;
  } else if (tid < 64) {
    float s = 0.f;
    for (int k = 0; k < 432; ++k) s += separt[(size_t)(b * 432 + k) * 64 + tid];
    sesum[b * 64 + tid] = s;
  }
}

// ============ P2a2: 8 segs -> msum ===========================================
__global__ void p2a2(const float* __restrict__ mpart2, float* __restrict__ msum)
{
  const int b = blockIdx.y;
  const int idx = blockIdx.x * 256 + threadIdx.x;
  float s = 0.f;
  #pragma unroll
  for (int k = 0; k < 8; ++k) s += mpart2[(size_t)(b * 8 + k) * 8192 + idx];
  msum[(size_t)b * 8192 + idx] = s;
}

// ============ P2b: G[m,n] = (WA@M)/sesum + bA; store f32 + swizzled f16 ======
__global__ void p2b(const float* __restrict__ WA_, const float* __restrict__ bA_,
                    const float* __restrict__ msum, const float* __restrict__ sesum,
                    float* __restrict__ g32, f16* __restrict__ g16)
{
  const int b = blockIdx.y;
  const int idx = blockIdx.x * 256 + threadIdx.x;
  const int m = idx >> 6, n = idx & 63;
  float s = 0.f;
  #pragma unroll 4
  for (int c = 0; c < 128; ++c) s += WA_[m * 128 + c] * msum[(size_t)b * 8192 + c * 64 + n];
  const float g = s / sesum[b * 64 + n] + bA_[m];
  g32[(size_t)b * 8192 + m * 64 + n] = g;
  g16[(size_t)b * 8192 + m * 64 + ((((n >> 3) ^ (m & 7)) << 3) | (n & 7))] = (f16)g;
}

// ============ P3: av = softmax_n(V); mu[n]=sum av; C = av@av^T (MFMA) ========
// grid (108, B), T=16 tiles.
__global__ __launch_bounds__(256, 2) void p3_cov(
    const f16* __restrict__ vv, float* __restrict__ cpart, float* __restrict__ mupart)
{
  __shared__ __align__(16) f16 AV[64 * 64];  // av[n][l] swizzled
  __shared__ float colp[4][64];
  __shared__ float rsl[64];
  const int tid = threadIdx.x, b = blockIdx.y, blk = blockIdx.x;
  const int ln = tid & 63, wid = tid >> 6;
  const int nst = tid >> 2, lcs = (tid & 3) * 16;

  f32x4 cacc[4];
  #pragma unroll
  for (int j = 0; j < 4; ++j) cacc[j] = (f32x4){0.f, 0.f, 0.f, 0.f};
  float muacc = 0.f;

  for (int t = 0; t < 16; ++t) {
    const int l0 = (blk * 16 + t) * 64;
    __syncthreads();
    float e[16];
    const int i0 = nst * 64 + ((((lcs >> 3) ^ (nst & 7))) << 3);
    const int i1 = nst * 64 + (((((lcs >> 3) + 1) ^ (nst & 7))) << 3);
    {
      const f16* vp = vv + (size_t)(b * 64 + nst) * LTOT + l0 + lcs;
      const f16x8 v0 = *(const f16x8*)&vp[0];
      const f16x8 v1 = *(const f16x8*)&vp[8];
      f16x8 w0, w1;
      #pragma unroll
      for (int j = 0; j < 8; ++j) {
        e[j] = __expf((float)v0[j]);
        e[8 + j] = __expf((float)v1[j]);
        w0[j] = (f16)e[j];
        w1[j] = (f16)e[8 + j];
      }
      *(f16x8*)&AV[i0] = w0;
      *(f16x8*)&AV[i1] = w1;
    }
    __syncthreads();
    {  // column sums over n (4 threads per l)
      const int l = tid >> 2, q = tid & 3;
      float s = 0.f;
      #pragma unroll
      for (int k = 0; k < 16; ++k) {
        const int n = q * 16 + k;
        s += (float)AV[n * 64 + ((((l >> 3) ^ (n & 7)) << 3) | (l & 7))];
      }
      colp[q][l] = s;
    }
    __syncthreads();
    if (tid < 64) rsl[tid] = 1.f / (colp[0][tid] + colp[1][tid] + colp[2][tid] + colp[3][tid]);
    __syncthreads();
    {  // rescale own row chunk, mu partial
      float rsv[16];
      #pragma unroll
      for (int k = 0; k < 4; ++k) {
        const float4 rv = *(const float4*)&rsl[lcs + k * 4];
        rsv[k * 4 + 0] = rv.x; rsv[k * 4 + 1] = rv.y;
        rsv[k * 4 + 2] = rv.z; rsv[k * 4 + 3] = rv.w;
      }
      float rp = 0.f;
      f16x8 w0, w1;
      #pragma unroll
      for (int j = 0; j < 8; ++j) {
        const float a0 = e[j] * rsv[j];
        const float a1 = e[8 + j] * rsv[8 + j];
        rp += a0 + a1;
        w0[j] = (f16)a0;
        w1[j] = (f16)a1;
      }
      *(f16x8*)&AV[i0] = w0;
      *(f16x8*)&AV[i1] = w1;
      rp += __shfl_xor(rp, 1);
      rp += __shfl_xor(rp, 2);
      if ((tid & 3) == 0) muacc += rp;
    }
    __syncthreads();
    #pragma unroll
    for (int ks = 0; ks < 2; ++ks) {
      const int lblk = ks * 4 + (ln >> 4);
      const int row = wid * 16 + (ln & 15);
      const f16x8 af = *(const f16x8*)&AV[row * 64 + ((lblk ^ (row & 7)) << 3)];
      #pragma unroll
      for (int nct = 0; nct < 4; ++nct) {
        const int rb = nct * 16 + (ln & 15);
        const f16x8 bf = *(const f16x8*)&AV[rb * 64 + ((lblk ^ (rb & 7)) << 3)];
        cacc[nct] = MFMA16(af, bf, cacc[nct]);
      }
    }
  }
  float* cp = cpart + (size_t)(b * 108 + blk) * 4096;
  #pragma unroll
  for (int nct = 0; nct < 4; ++nct)
    #pragma unroll
    for (int r = 0; r < 4; ++r) {
      const int n = wid * 16 + (ln >> 4) * 4 + r;
      const int np = nct * 16 + (ln & 15);
      cp[n * 64 + np] = cacc[nct][r];
    }
  if ((tid & 3) == 0) mupart[(size_t)(b * 108 + blk) * 64 + nst] = muacc;
}

// ============ P4a: reduce C partials + mu partials ===========================
__global__ void p4a(const float* __restrict__ cpart, const float* __restrict__ mupart,
                    float* __restrict__ csum, float* __restrict__ musum)
{
  const int b = blockIdx.y, bx = blockIdx.x, tid = threadIdx.x;
  if (bx < 64) {
    const int idx = bx * 64 + (tid >> 2), q = tid & 3;
    float s = 0.f;
    for (int k = q; k < 108; k += 4) s += cpart[(size_t)(b * 108 + k) * 4096 + idx];
    s += __shfl_xor(s, 1);
    s += __shfl_xor(s, 2);
    if (q == 0) csum[(size_t)b * 4096 + idx] = s;
  } else if (tid < 64) {
    float s = 0.f;
    for (int k = 0; k < 108; ++k) s += mupart[(size_t)(b * 108 + k) * 64 + tid];
    musum[b * 64 + tid] = s;
  }
}

// ============ P4b: mean = G@mu/L; E[Z^2] = (G C G^T)_mm / L -> mean,rsig =====
__global__ void p4b(const float* __restrict__ csum, const float* __restrict__ musum,
                    const float* __restrict__ g32, float* __restrict__ mr)
{
  __shared__ __align__(16) float CL[4096];
  __shared__ __align__(16) float GLs[32 * 68];
  __shared__ float MUL[64];
  const int tid = threadIdx.x, b = blockIdx.y, bx = blockIdx.x;
  #pragma unroll
  for (int k = 0; k < 16; ++k) CL[k * 256 + tid] = csum[(size_t)b * 4096 + k * 256 + tid];
  #pragma unroll
  for (int k = 0; k < 8; ++k) {
    const int idx = k * 256 + tid;
    const int m_ = idx >> 6, n_ = idx & 63;
    GLs[m_ * 68 + n_] = g32[(size_t)b * 8192 + (bx * 32 + m_) * 64 + n_];
  }
  if (tid < 64) MUL[tid] = musum[b * 64 + tid];
  __syncthreads();
  const int mrow = (tid >> 3) * 68, oct = tid & 7;
  float q = 0.f;
  #pragma unroll
  for (int q4 = 0; q4 < 2; ++q4) {
    const int npb = oct * 8 + q4 * 4;
    float t0 = 0.f, t1 = 0.f, t2 = 0.f, t3 = 0.f;
    #pragma unroll 8
    for (int n = 0; n < 64; ++n) {
      const float4 cv = *(const float4*)&CL[n * 64 + npb];
      const float g = GLs[mrow + n];
      t0 += g * cv.x; t1 += g * cv.y; t2 += g * cv.z; t3 += g * cv.w;
    }
    const float4 gq = *(const float4*)&GLs[mrow + npb];
    q += t0 * gq.x + t1 * gq.y + t2 * gq.z + t3 * gq.w;
  }
  q += __shfl_xor(q, 1); q += __shfl_xor(q, 2); q += __shfl_xor(q, 4);
  if (oct == 0) {
    float meanq = 0.f;
    #pragma unroll 8
    for (int n = 0; n < 64; ++n) meanq += GLs[mrow + n] * MUL[n];
    const int m = bx * 32 + (tid >> 3);
    const float mean = meanq / (float)LTOT;
    const float var = fmaxf(q / (float)LTOT - mean * mean, 0.f);
    mr[(b * 128 + m) * 2] = mean;
    mr[(b * 128 + m) * 2 + 1] = rsqrtf(var + EPSV);
  }
}

// ============ P5: av = softmax_n(V); Z = G@av; write normalized ==============
// grid (432, B), T=4 tiles.
__global__ __launch_bounds__(256, 2) void p5_z(
    const f16* __restrict__ vv, const f16* __restrict__ g16,
    const float* __restrict__ mr, float* __restrict__ out)
{
  __shared__ __align__(16) f16 GL[128 * 64];
  __shared__ __align__(16) f16 AVT[64 * 64];  // av^T[l][n] swizzled
  __shared__ float colp[4][64];
  __shared__ float rsl[64];
  const int tid = threadIdx.x, b = blockIdx.y, blk = blockIdx.x;
  const int ln = tid & 63, wid = tid >> 6;

  #pragma unroll
  for (int k = 0; k < 4; ++k) {
    const int i8 = k * 256 + tid;
    *(f16x8*)&GL[i8 * 8] = *(const f16x8*)&g16[(size_t)b * 8192 + i8 * 8];
  }
  float mean_[2][4], rsig_[2][4];
  #pragma unroll
  for (int crt = 0; crt < 2; ++crt)
    #pragma unroll
    for (int r = 0; r < 4; ++r) {
      const int m = (wid * 2 + crt) * 16 + (ln >> 4) * 4 + r;
      mean_[crt][r] = mr[(b * 128 + m) * 2];
      rsig_[crt][r] = mr[(b * 128 + m) * 2 + 1];
    }
  __syncthreads();
  f16x8 gf[2][2];
  #pragma unroll
  for (int crt = 0; crt < 2; ++crt)
    #pragma unroll
    for (int ks = 0; ks < 2; ++ks) {
      const int m = (wid * 2 + crt) * 16 + (ln & 15);
      const int nblk = ks * 4 + (ln >> 4);
      gf[crt][ks] = *(const f16x8*)&GL[m * 64 + ((nblk ^ (m & 7)) << 3)];
    }
  const int nst = tid >> 2, lcs = (tid & 3) * 16;

  for (int t = 0; t < 4; ++t) {
    const int l0 = (blk * 4 + t) * 64;
    __syncthreads();
    {  // stage e into AVT (transposed scatter)
      const f16* vp = vv + (size_t)(b * 64 + nst) * LTOT + l0 + lcs;
      const f16x8 v0 = *(const f16x8*)&vp[0];
      const f16x8 v1 = *(const f16x8*)&vp[8];
      #pragma unroll
      for (int j = 0; j < 8; ++j) {
        const int l = lcs + j;
        AVT[l * 64 + ((((nst >> 3) ^ (l & 7)) << 3) | (nst & 7))] = (f16)__expf((float)v0[j]);
      }
      #pragma unroll
      for (int j = 0; j < 8; ++j) {
        const int l = lcs + 8 + j;
        AVT[l * 64 + ((((nst >> 3) ^ (l & 7)) << 3) | (nst & 7))] = (f16)__expf((float)v1[j]);
      }
    }
    __syncthreads();
    {  // column sums of V-softmax = row sums of AVT
      const int l = tid >> 2, q = tid & 3;
      const f16x8 a0 = *(const f16x8*)&AVT[l * 64 + (((q * 2) ^ (l & 7)) << 3)];
      const f16x8 a1 = *(const f16x8*)&AVT[l * 64 + (((q * 2 + 1) ^ (l & 7)) << 3)];
      float s = 0.f;
      #pragma unroll
      for (int j = 0; j < 8; ++j) s += (float)a0[j] + (float)a1[j];
      colp[q][l] = s;
    }
    __syncthreads();
    if (tid < 64) rsl[tid] = 1.f / (colp[0][tid] + colp[1][tid] + colp[2][tid] + colp[3][tid]);
    __syncthreads();
    {  // rescale row l by rsl[l]
      const int l = tid >> 2, q = tid & 3;
      const float rv = rsl[l];
      const int j0 = l * 64 + (((q * 2) ^ (l & 7)) << 3);
      const int j1 = l * 64 + (((q * 2 + 1) ^ (l & 7)) << 3);
      f16x8 a0 = *(f16x8*)&AVT[j0];
      f16x8 a1 = *(f16x8*)&AVT[j1];
      #pragma unroll
      for (int j = 0; j < 8; ++j) {
        a0[j] = (f16)((float)a0[j] * rv);
        a1[j] = (f16)((float)a1[j] * rv);
      }
      *(f16x8*)&AVT[j0] = a0;
      *(f16x8*)&AVT[j1] = a1;
    }
    __syncthreads();
    // Z = G @ av, normalize, store
    #pragma unroll
    for (int ct = 0; ct < 4; ++ct) {
      f32x4 z0 = {0.f, 0.f, 0.f, 0.f}, z1 = {0.f, 0.f, 0.f, 0.f};
      #pragma unroll
      for (int ks = 0; ks < 2; ++ks) {
        const int l = ct * 16 + (ln & 15);
        const int nblk = ks * 4 + (ln >> 4);
        const f16x8 bf = *(const f16x8*)&AVT[l * 64 + ((nblk ^ (l & 7)) << 3)];
        z0 = MFMA16(gf[0][ks], bf, z0);
        z1 = MFMA16(gf[1][ks], bf, z1);
      }
      const int lcol = l0 + ct * 16 + (ln & 15);
      #pragma unroll
      for (int r = 0; r < 4; ++r) {
        const int m0 = (wid * 2 + 0) * 16 + (ln >> 4) * 4 + r;
        const int m1 = (wid * 2 + 1) * 16 + (ln >> 4) * 4 + r;
        out[(size_t)(b * 128 + m0) * LTOT + lcol] = (z0[r] - mean_[0][r]) * rsig_[0][r];
        out[(size_t)(b * 128 + m1) * LTOT + lcol] = (z1[r] - mean_[1][r]) * rsig_[1][r];
      }
    }
  }
}

extern "C" void kernel_launch(void* const* d_in, const int* in_sizes, int n_in,
                              void* d_out, int out_size, void* d_ws, size_t ws_size,
                              hipStream_t stream)
{
  const float* x  = (const float*)d_in[0];
  const float* WA = (const float*)d_in[1];
  const float* bA = (const float*)d_in[2];
  const float* WB = (const float*)d_in[3];
  const float* bB = (const float*)d_in[4];
  const float* WV = (const float*)d_in[5];
  const float* bV = (const float*)d_in[6];
  float* out = (float*)d_out;

  float* w = (float*)d_ws;
  float* mpart  = w;                       // 2*432*8192 = 7,077,888
  float* mpart2 = mpart + 7077888;         // 2*8*8192   =   131,072
  float* separt = mpart2 + 131072;         // 2*432*64   =    55,296
  float* msum   = separt + 55296;          // 2*8192     =    16,384
  float* sesum  = msum + 16384;            //                    128
  float* g32    = sesum + 128;             // 2*8192     =    16,384
  f16*   g16f   = (f16*)(g32 + 16384);     // 16,384 f16 (8192 f32 slots)
  f16*   vvf    = g16f + 16384;            // 2*64*L f16 = 14,155,776 hw
  float* cpart  = (float*)(vvf + 14155776);// 2*108*4096 =   884,736
  float* mupart = cpart + 884736;          // 2*108*64   =    13,824
  float* csum   = mupart + 13824;          // 2*4096     =     8,192
  float* musum  = csum + 8192;             //                    128
  float* mr     = musum + 128;             //                    512

  p1_proj_m<<<dim3(432, 2), 256, 0, stream>>>(x, WB, bB, WV, bV, vvf, mpart, separt);
  p2a<<<dim3(257, 2), 256, 0, stream>>>(mpart, separt, mpart2, sesum);
  p2a2<<<dim3(32, 2), 256, 0, stream>>>(mpart2, msum);
  p2b<<<dim3(32, 2), 256, 0, stream>>>(WA, bA, msum, sesum, g32, g16f);
  p3_cov<<<dim3(108, 2), 256, 0, stream>>>(vvf, cpart, mupart);
  p4a<<<dim3(65, 2), 256, 0, stream>>>(cpart, mupart, csum, musum);
  p4b<<<dim3(4, 2), 256, 0, stream>>>(csum, musum, g32, mr);
  p5_z<<<dim3(432, 2), 256, 0, stream>>>(vvf, g16f, mr, out);
}

// Round 4
// 137.807 us; speedup vs baseline: 3.9779x; 1.0383x over previous
//
#include <hip/hip_runtime.h>

#define LTOT 110592   // 48*48*48
#define EPSV 1e-5f

typedef _Float16 f16;
typedef __attribute__((ext_vector_type(4))) _Float16 f16x4;
typedef __attribute__((ext_vector_type(8))) _Float16 f16x8;
typedef __attribute__((ext_vector_type(4))) float f32x4;

#define MFMA16(a, b, c) __builtin_amdgcn_mfma_f32_16x16x32_f16(a, b, c, 0, 0, 0)

__device__ __forceinline__ f16x8 ld_w8(const float* p) {
  const float4 a = *(const float4*)p;
  const float4 b = *(const float4*)(p + 4);
  f16x8 f;
  f[0] = (f16)a.x; f[1] = (f16)a.y; f[2] = (f16)a.z; f[3] = (f16)a.w;
  f[4] = (f16)b.x; f[5] = (f16)b.y; f[6] = (f16)b.z; f[7] = (f16)b.w;
  return f;
}

// ============ P1: BmT,V proj (MFMA); e->EL; av-softmax->av_g; Mt += EL@XC ====
// grid (432, B), 4 tiles of 64 cols each. All LDS accesses vectorized.
__global__ __launch_bounds__(256, 2) void p1_proj_m(
    const float* __restrict__ x,
    const float* __restrict__ WB_, const float* __restrict__ bB_,
    const float* __restrict__ WV_, const float* __restrict__ bV_,
    f16* __restrict__ av_g, float* __restrict__ mpart, float* __restrict__ separt)
{
  __shared__ __align__(16) f16 XT[64 * 128];  // [l][c^((l&7)<<3)]
  __shared__ __align__(16) f16 XC[128 * 64];  // [c][l^((c&7)<<3)]
  __shared__ __align__(16) f16 EL[64 * 64];   // [n][l^((n&7)<<3)]
  __shared__ __align__(16) f16 AVT[64 * 64];  // [l][n^((l&7)<<3)] (unscaled exp)
  __shared__ float colp[4][64];
  const int tid = threadIdx.x, b = blockIdx.y, blk = blockIdx.x;
  const int ln = tid & 63, w = tid >> 6, g = ln >> 4;

  // W fragments (rows n = w*16 + (ln&15), both as row-major-over-c frags)
  const int nB = w * 16 + (ln & 15);
  f16x8 wbf[4], wvf[4];
  #pragma unroll
  for (int ks = 0; ks < 4; ++ks) {
    wbf[ks] = ld_w8(&WB_[nB * 128 + ks * 32 + g * 8]);
    wvf[ks] = ld_w8(&WV_[nB * 128 + ks * 32 + g * 8]);
  }
  const float sB = bB_[nB];
  float biasV[4];
  #pragma unroll
  for (int r = 0; r < 4; ++r) biasV[r] = bV_[w * 16 + g * 4 + r];

  f32x4 macc[8];
  #pragma unroll
  for (int i = 0; i < 8; ++i) macc[i] = (f32x4){0.f, 0.f, 0.f, 0.f};
  float se = 0.f;

  const int xt_co = tid & 15, xt_lq = tid >> 4;  // XT stage: 8c x 4l
  const int xc_lo = tid & 7,  xc_c4 = tid >> 3;  // XC stage: 4c x 8l
  const size_t xb = (size_t)b * 128 * LTOT;

  for (int t = 0; t < 4; ++t) {
    const int l0 = (blk * 4 + t) * 64;
    __syncthreads();
    // ---- stage XT [l][c] (vector writes) ----
    {
      float4 xr[8];
      #pragma unroll
      for (int j = 0; j < 8; ++j)
        xr[j] = *(const float4*)&x[xb + (size_t)(xt_co * 8 + j) * LTOT + l0 + xt_lq * 4];
      #pragma unroll
      for (int i = 0; i < 4; ++i) {
        const int l = xt_lq * 4 + i;
        f16x8 v;
        #pragma unroll
        for (int j = 0; j < 8; ++j) v[j] = (f16)(((const float*)&xr[j])[i]);
        *(f16x8*)&XT[l * 128 + ((xt_co * 8) ^ ((l & 7) << 3))] = v;
      }
    }
    // ---- stage XC [c][l] (vector writes; 2nd read L2-hits) ----
    #pragma unroll
    for (int i = 0; i < 4; ++i) {
      const int c = xc_c4 * 4 + i;
      const float4 a = *(const float4*)&x[xb + (size_t)c * LTOT + l0 + xc_lo * 8];
      const float4 d = *(const float4*)&x[xb + (size_t)c * LTOT + l0 + xc_lo * 8 + 4];
      f16x8 v;
      v[0] = (f16)a.x; v[1] = (f16)a.y; v[2] = (f16)a.z; v[3] = (f16)a.w;
      v[4] = (f16)d.x; v[5] = (f16)d.y; v[6] = (f16)d.z; v[7] = (f16)d.w;
      *(f16x8*)&XC[c * 64 + ((xc_lo * 8) ^ ((c & 7) << 3))] = v;
    }
    __syncthreads();
    // ---- proj: BmT (A=XT,B=WB) and V (A=WV,B=XT) share XT frags ----
    f32x4 aB[4], aV[4];
    #pragma unroll
    for (int lt = 0; lt < 4; ++lt) {
      aB[lt] = (f32x4){0.f, 0.f, 0.f, 0.f};
      aV[lt] = (f32x4){0.f, 0.f, 0.f, 0.f};
      const int l = lt * 16 + (ln & 15);
      #pragma unroll
      for (int ks = 0; ks < 4; ++ks) {
        const f16x8 xf = *(const f16x8*)&XT[l * 128 + (((ks * 4 + g) * 8) ^ ((l & 7) << 3))];
        aB[lt] = MFMA16(xf, wbf[ks], aB[lt]);
        aV[lt] = MFMA16(wvf[ks], xf, aV[lt]);
      }
    }
    // ---- e = exp(BmT + bias) -> EL (vector f16x4), sumexp ----
    #pragma unroll
    for (int lt = 0; lt < 4; ++lt) {
      f16x4 ev4;
      #pragma unroll
      for (int r = 0; r < 4; ++r) {
        const float e = __expf(aB[lt][r] + sB);
        se += e;
        ev4[r] = (f16)e;
      }
      const int lq = lt * 16 + g * 4;
      *(f16x4*)&EL[nB * 64 + (lq ^ ((nB & 7) << 3))] = ev4;
    }
    // ---- ev = exp(V + bias) -> AVT (unscaled), column-sum partials ----
    float cs[4];
    #pragma unroll
    for (int ct = 0; ct < 4; ++ct) {
      f16x4 av4;
      float s = 0.f;
      #pragma unroll
      for (int r = 0; r < 4; ++r) {
        const float e = __expf(aV[ct][r] + biasV[r]);
        s += e;
        av4[r] = (f16)e;
      }
      cs[ct] = s;
      const int l = ct * 16 + (ln & 15);
      *(f16x4*)&AVT[l * 64 + ((w * 16 + g * 4) ^ ((l & 7) << 3))] = av4;
    }
    #pragma unroll
    for (int ct = 0; ct < 4; ++ct) {
      cs[ct] += __shfl_xor(cs[ct], 16);
      cs[ct] += __shfl_xor(cs[ct], 32);
    }
    {
      const float v = (g == 0) ? cs[0] : (g == 1) ? cs[1] : (g == 2) ? cs[2] : cs[3];
      colp[w][g * 16 + (ln & 15)] = v;
    }
    __syncthreads();
    // ---- scale + store av tile to global [l][n] ----
    {
      const int l = tid >> 2, q = tid & 3;
      const float rs = 1.f / (colp[0][l] + colp[1][l] + colp[2][l] + colp[3][l]);
      f16x8 a0 = *(const f16x8*)&AVT[l * 64 + ((q * 16) ^ ((l & 7) << 3))];
      f16x8 a1 = *(const f16x8*)&AVT[l * 64 + ((q * 16 + 8) ^ ((l & 7) << 3))];
      #pragma unroll
      for (int j = 0; j < 8; ++j) {
        a0[j] = (f16)((float)a0[j] * rs);
        a1[j] = (f16)((float)a1[j] * rs);
      }
      f16* gp = av_g + ((size_t)b * LTOT + l0 + l) * 64 + q * 16;
      *(f16x8*)&gp[0] = a0;
      *(f16x8*)&gp[8] = a1;
    }
    // ---- Mt[n][c] += EL(A) @ XC(B), K=64 ----
    {
      f16x8 el[2];
      #pragma unroll
      for (int ks = 0; ks < 2; ++ks)
        el[ks] = *(const f16x8*)&EL[nB * 64 + ((ks * 32 + g * 8) ^ ((nB & 7) << 3))];
      #pragma unroll
      for (int cblk = 0; cblk < 8; ++cblk) {
        const int c = cblk * 16 + (ln & 15);
        #pragma unroll
        for (int ks = 0; ks < 2; ++ks) {
          const f16x8 xcf = *(const f16x8*)&XC[c * 64 + ((ks * 32 + g * 8) ^ ((c & 7) << 3))];
          macc[cblk] = MFMA16(el[ks], xcf, macc[cblk]);
        }
      }
    }
  }
  // ---- write Mt partial [n][c] + sumexp partial ----
  float* mp = mpart + (size_t)(b * 432 + blk) * 8192;
  #pragma unroll
  for (int cblk = 0; cblk < 8; ++cblk)
    #pragma unroll
    for (int r = 0; r < 4; ++r)
      mp[(w * 16 + g * 4 + r) * 128 + cblk * 16 + (ln & 15)] = macc[cblk][r];
  se += __shfl_xor(se, 16);
  se += __shfl_xor(se, 32);
  if (ln < 16) separt[(size_t)(b * 432 + blk) * 64 + w * 16 + ln] = se;
}

// ============ P2a: Mt partials 432 -> 8 segs; sumexp 432 -> 1 ================
__global__ void p2a(const float* __restrict__ mpart, const float* __restrict__ separt,
                    float* __restrict__ mpart2, float* __restrict__ sesum)
{
  const int b = blockIdx.y, bx = blockIdx.x, tid = threadIdx.x;
  if (bx < 256) {
    const int seg = bx >> 5, chunk = bx & 31;
    const int idx = chunk * 256 + tid;
    float s = 0.f;
    for (int j = 0; j < 54; ++j)
      s += mpart[(size_t)(b * 432 + seg * 54 + j) * 8192 + idx];
    mpart2[(size_t)(b * 8 + seg) * 8192 + idx] = s;
  } else if (tid < 64) {
    float s = 0.f;
    for (int k = 0; k < 432; ++k) s += separt[(size_t)(b * 432 + k) * 64 + tid];
    sesum[b * 64 + tid] = s;
  }
}

// ============ P2a2: 8 segs -> msum [n][c] ====================================
__global__ void p2a2(const float* __restrict__ mpart2, float* __restrict__ msum)
{
  const int b = blockIdx.y;
  const int idx = blockIdx.x * 256 + threadIdx.x;
  float s = 0.f;
  #pragma unroll
  for (int k = 0; k < 8; ++k) s += mpart2[(size_t)(b * 8 + k) * 8192 + idx];
  msum[(size_t)b * 8192 + idx] = s;
}

// ============ P2b: G[m,n] = (WA@M)/sesum + bA; f32 [m][n] + swizzled f16 =====
__global__ void p2b(const float* __restrict__ WA_, const float* __restrict__ bA_,
                    const float* __restrict__ msum, const float* __restrict__ sesum,
                    float* __restrict__ g32, f16* __restrict__ g16)
{
  const int b = blockIdx.y;
  const int idx = blockIdx.x * 256 + threadIdx.x;
  const int m = idx >> 6, n = idx & 63;
  float s = 0.f;
  #pragma unroll 4
  for (int c = 0; c < 128; ++c) s += WA_[m * 128 + c] * msum[(size_t)b * 8192 + n * 128 + c];
  const float gv = s / sesum[b * 64 + n] + bA_[m];
  g32[(size_t)b * 8192 + m * 64 + n] = gv;
  g16[(size_t)b * 8192 + m * 64 + (n ^ ((m & 7) << 3))] = (f16)gv;
}

// ============ P3: C = av@av^T, mu = row-sums (reads av_g) ====================
// grid (216, B), 8 tiles each.
__global__ __launch_bounds__(256, 2) void p3_cov(
    const f16* __restrict__ av_g, float* __restrict__ cpart, float* __restrict__ mupart)
{
  __shared__ __align__(16) f16 AV[64 * 64];  // [n][l^((n&7)<<3)]
  const int tid = threadIdx.x, b = blockIdx.y, blk = blockIdx.x;
  const int ln = tid & 63, w = tid >> 6, g = ln >> 4;
  const int nq4 = (tid & 15) * 4, lq4 = (tid >> 4) * 4;  // stage: 4l x 4n
  const int nmu = tid >> 2, qmu = tid & 3;

  f32x4 cacc[4];
  #pragma unroll
  for (int j = 0; j < 4; ++j) cacc[j] = (f32x4){0.f, 0.f, 0.f, 0.f};
  float muacc = 0.f;

  for (int t = 0; t < 8; ++t) {
    const int l0 = (blk * 8 + t) * 64;
    __syncthreads();
    {  // stage: read [l][n] quads, transpose in regs, write [n][l] quads
      f16x4 rd[4];
      #pragma unroll
      for (int i = 0; i < 4; ++i)
        rd[i] = *(const f16x4*)&av_g[((size_t)b * LTOT + l0 + lq4 + i) * 64 + nq4];
      #pragma unroll
      for (int j = 0; j < 4; ++j) {
        const int n = nq4 + j;
        f16x4 wr;
        #pragma unroll
        for (int i = 0; i < 4; ++i) wr[i] = rd[i][j];
        *(f16x4*)&AV[n * 64 + (lq4 ^ ((n & 7) << 3))] = wr;
      }
    }
    __syncthreads();
    {  // mu partial: row sums
      const f16x8 a0 = *(const f16x8*)&AV[nmu * 64 + ((qmu * 16) ^ ((nmu & 7) << 3))];
      const f16x8 a1 = *(const f16x8*)&AV[nmu * 64 + ((qmu * 16 + 8) ^ ((nmu & 7) << 3))];
      #pragma unroll
      for (int j = 0; j < 8; ++j) muacc += (float)a0[j] + (float)a1[j];
    }
    // C MFMA: wave w owns rows n = w*16..+16
    const int nA = w * 16 + (ln & 15);
    f16x8 caf[2];
    #pragma unroll
    for (int ks = 0; ks < 2; ++ks)
      caf[ks] = *(const f16x8*)&AV[nA * 64 + ((ks * 32 + g * 8) ^ ((nA & 7) << 3))];
    #pragma unroll
    for (int nct = 0; nct < 4; ++nct) {
      const int nb = nct * 16 + (ln & 15);
      #pragma unroll
      for (int ks = 0; ks < 2; ++ks) {
        const f16x8 cbf = *(const f16x8*)&AV[nb * 64 + ((ks * 32 + g * 8) ^ ((nb & 7) << 3))];
        cacc[nct] = MFMA16(caf[ks], cbf, cacc[nct]);
      }
    }
  }
  float* cp = cpart + (size_t)(b * 216 + blk) * 4096;
  #pragma unroll
  for (int nct = 0; nct < 4; ++nct)
    #pragma unroll
    for (int r = 0; r < 4; ++r)
      cp[(w * 16 + g * 4 + r) * 64 + nct * 16 + (ln & 15)] = cacc[nct][r];
  muacc += __shfl_xor(muacc, 1);
  muacc += __shfl_xor(muacc, 2);
  if (qmu == 0) mupart[(size_t)(b * 216 + blk) * 64 + nmu] = muacc;
}

// ============ P4a: reduce C partials + mu partials ===========================
__global__ void p4a(const float* __restrict__ cpart, const float* __restrict__ mupart,
                    float* __restrict__ csum, float* __restrict__ musum)
{
  const int b = blockIdx.y, bx = blockIdx.x, tid = threadIdx.x;
  if (bx < 64) {
    const int idx = bx * 64 + (tid >> 2), q = tid & 3;
    float s = 0.f;
    for (int k = q; k < 216; k += 4) s += cpart[(size_t)(b * 216 + k) * 4096 + idx];
    s += __shfl_xor(s, 1);
    s += __shfl_xor(s, 2);
    if (q == 0) csum[(size_t)b * 4096 + idx] = s;
  } else if (tid < 64) {
    float s = 0.f;
    for (int k = 0; k < 216; ++k) s += mupart[(size_t)(b * 216 + k) * 64 + tid];
    musum[b * 64 + tid] = s;
  }
}

// ============ P4b: mean = G@mu/L; E[Z^2] = (G C G^T)_mm / L -> mean,rsig =====
__global__ void p4b(const float* __restrict__ csum, const float* __restrict__ musum,
                    const float* __restrict__ g32, float* __restrict__ mr)
{
  __shared__ __align__(16) float CL[4096];
  __shared__ __align__(16) float GLs[32 * 68];
  __shared__ float MUL[64];
  const int tid = threadIdx.x, b = blockIdx.y, bx = blockIdx.x;
  #pragma unroll
  for (int k = 0; k < 16; ++k) CL[k * 256 + tid] = csum[(size_t)b * 4096 + k * 256 + tid];
  #pragma unroll
  for (int k = 0; k < 8; ++k) {
    const int idx = k * 256 + tid;
    const int m_ = idx >> 6, n_ = idx & 63;
    GLs[m_ * 68 + n_] = g32[(size_t)b * 8192 + (bx * 32 + m_) * 64 + n_];
  }
  if (tid < 64) MUL[tid] = musum[b * 64 + tid];
  __syncthreads();
  const int mrow = (tid >> 3) * 68, oct = tid & 7;
  float q = 0.f;
  #pragma unroll
  for (int q4 = 0; q4 < 2; ++q4) {
    const int npb = oct * 8 + q4 * 4;
    float t0 = 0.f, t1 = 0.f, t2 = 0.f, t3 = 0.f;
    #pragma unroll 8
    for (int n = 0; n < 64; ++n) {
      const float4 cv = *(const float4*)&CL[n * 64 + npb];
      const float gv = GLs[mrow + n];
      t0 += gv * cv.x; t1 += gv * cv.y; t2 += gv * cv.z; t3 += gv * cv.w;
    }
    const float4 gq = *(const float4*)&GLs[mrow + npb];
    q += t0 * gq.x + t1 * gq.y + t2 * gq.z + t3 * gq.w;
  }
  q += __shfl_xor(q, 1); q += __shfl_xor(q, 2); q += __shfl_xor(q, 4);
  if (oct == 0) {
    float meanq = 0.f;
    #pragma unroll 8
    for (int n = 0; n < 64; ++n) meanq += GLs[mrow + n] * MUL[n];
    const int m = bx * 32 + (tid >> 3);
    const float mean = meanq / (float)LTOT;
    const float var = fmaxf(q / (float)LTOT - mean * mean, 0.f);
    mr[(b * 128 + m) * 2] = mean;
    mr[(b * 128 + m) * 2 + 1] = rsqrtf(var + EPSV);
  }
}

// ============ P5: Z = G@av (MFMA), write normalized ==========================
// grid (432, B), 4 tiles each.
__global__ __launch_bounds__(256, 2) void p5_z(
    const f16* __restrict__ av_g, const f16* __restrict__ g16,
    const float* __restrict__ mr, float* __restrict__ out)
{
  __shared__ __align__(16) f16 AVT[64 * 64];  // [l][n^((l&7)<<3)]
  const int tid = threadIdx.x, b = blockIdx.y, blk = blockIdx.x;
  const int ln = tid & 63, w = tid >> 6, g = ln >> 4;
  const int lst = tid & 63, pst = tid >> 6;

  // G fragments: wave w owns m = w*32..+32 (2 mct of 16)
  f16x8 gf[2][2];
  float mean_[2][4], rsig_[2][4];
  #pragma unroll
  for (int mct = 0; mct < 2; ++mct) {
    const int mA = w * 32 + mct * 16 + (ln & 15);
    #pragma unroll
    for (int ks = 0; ks < 2; ++ks)
      gf[mct][ks] = *(const f16x8*)&g16[(size_t)b * 8192 + mA * 64 +
                                        (((ks * 4 + g) * 8) ^ ((mA & 7) << 3))];
    #pragma unroll
    for (int r = 0; r < 4; ++r) {
      const int m = w * 32 + mct * 16 + g * 4 + r;
      mean_[mct][r] = mr[(b * 128 + m) * 2];
      rsig_[mct][r] = mr[(b * 128 + m) * 2 + 1];
    }
  }

  for (int t = 0; t < 4; ++t) {
    const int l0 = (blk * 4 + t) * 64;
    __syncthreads();
    {  // stage av tile: straight vector copy with swizzle
      const f16* gp = av_g + ((size_t)b * LTOT + l0 + lst) * 64 + pst * 16;
      const f16x8 a0 = *(const f16x8*)&gp[0];
      const f16x8 a1 = *(const f16x8*)&gp[8];
      *(f16x8*)&AVT[lst * 64 + ((pst * 16) ^ ((lst & 7) << 3))] = a0;
      *(f16x8*)&AVT[lst * 64 + ((pst * 16 + 8) ^ ((lst & 7) << 3))] = a1;
    }
    __syncthreads();
    #pragma unroll
    for (int lt = 0; lt < 4; ++lt) {
      const int l = lt * 16 + (ln & 15);
      f16x8 avf[2];
      #pragma unroll
      for (int ks = 0; ks < 2; ++ks)
        avf[ks] = *(const f16x8*)&AVT[l * 64 + (((ks * 4 + g) * 8) ^ ((l & 7) << 3))];
      #pragma unroll
      for (int mct = 0; mct < 2; ++mct) {
        f32x4 z = {0.f, 0.f, 0.f, 0.f};
        #pragma unroll
        for (int ks = 0; ks < 2; ++ks) z = MFMA16(gf[mct][ks], avf[ks], z);
        #pragma unroll
        for (int r = 0; r < 4; ++r) {
          const int m = w * 32 + mct * 16 + g * 4 + r;
          out[(size_t)(b * 128 + m) * LTOT + l0 + l] =
              (z[r] - mean_[mct][r]) * rsig_[mct][r];
        }
      }
    }
  }
}

extern "C" void kernel_launch(void* const* d_in, const int* in_sizes, int n_in,
                              void* d_out, int out_size, void* d_ws, size_t ws_size,
                              hipStream_t stream)
{
  const float* x  = (const float*)d_in[0];
  const float* WA = (const float*)d_in[1];
  const float* bA = (const float*)d_in[2];
  const float* WB = (const float*)d_in[3];
  const float* bB = (const float*)d_in[4];
  const float* WV = (const float*)d_in[5];
  const float* bV = (const float*)d_in[6];
  float* out = (float*)d_out;

  float* w = (float*)d_ws;
  float* mpart  = w;                        // 2*432*8192 = 7,077,888 f
  float* mpart2 = mpart + 7077888;          // 2*8*8192
  float* separt = mpart2 + 131072;          // 2*432*64
  float* msum   = separt + 55296;           // 2*8192
  float* sesum  = msum + 16384;             // 128
  float* g32    = sesum + 128;              // 2*8192
  f16*   g16f   = (f16*)(g32 + 16384);      // 16,384 f16
  f16*   av_g   = g16f + 16384;             // 2*L*64 f16 = 14,155,776
  float* cpart  = (float*)(av_g + 14155776);// 2*216*4096 = 1,769,472 f
  float* mupart = cpart + 1769472;          // 2*216*64
  float* csum   = mupart + 27648;           // 2*4096
  float* musum  = csum + 8192;              // 128
  float* mr     = musum + 128;              // 512

  p1_proj_m<<<dim3(432, 2), 256, 0, stream>>>(x, WB, bB, WV, bV, av_g, mpart, separt);
  p2a<<<dim3(257, 2), 256, 0, stream>>>(mpart, separt, mpart2, sesum);
  p2a2<<<dim3(32, 2), 256, 0, stream>>>(mpart2, msum);
  p2b<<<dim3(32, 2), 256, 0, stream>>>(WA, bA, msum, sesum, g32, g16f);
  p3_cov<<<dim3(216, 2), 256, 0, stream>>>(av_g, cpart, mupart);
  p4a<<<dim3(65, 2), 256, 0, stream>>>(cpart, mupart, csum, musum);
  p4b<<<dim3(4, 2), 256, 0, stream>>>(csum, musum, g32, mr);
  p5_z<<<dim3(432, 2), 256, 0, stream>>>(av_g, g16f, mr, out);
}